// Round 3
// baseline (311.149 us; speedup 1.0000x reference)
//
#include <hip/hip_runtime.h>

typedef unsigned long long u64;

#define HW 3136      // 56*56
#define NPIX 100352  // 32*3136

// ---- pack weights: [co][tap] -> 4 x u64 (256 ci bits) + per-tap popcount ---
__global__ __launch_bounds__(256) void pack_w_kernel(const float* __restrict__ W,
                                                     u64* __restrict__ wp,
                                                     unsigned short* __restrict__ pw) {
    int t = blockIdx.x * 256 + threadIdx.x;   // co*9 + tap, 2304 total (9 blocks)
    int co = t / 9, tap = t % 9;
    u64 b[4] = {0, 0, 0, 0};
    for (int ci = 0; ci < 256; ++ci) {
        float v = W[(size_t)(co * 256 + ci) * 9 + tap];
        if (v >= 0.f) b[ci >> 6] |= 1ull << (ci & 63);
    }
    u64* dst = wp + (size_t)t * 4;
    dst[0] = b[0]; dst[1] = b[1]; dst[2] = b[2]; dst[3] = b[3];
    pw[t] = (unsigned short)(__popcll(b[0]) + __popcll(b[1]) + __popcll(b[2]) + __popcll(b[3]));
}

// ---- pack activations: [n][h][w] -> 4 x u64 --------------------------------
__global__ __launch_bounds__(256) void pack_x_kernel(const float* __restrict__ x,
                                                     u64* __restrict__ xp) {
    int s = blockIdx.x * 256 + threadIdx.x;   // pixel in [0, 100352)
    int word = blockIdx.y;                    // 0..3 (64 channels each)
    int n = s / HW, hw = s % HW;
    const float* px = x + (size_t)(n * 256 + word * 64) * HW + hw;
    u64 b = 0;
    #pragma unroll 8
    for (int ci = 0; ci < 64; ++ci) {
        float v = px[(size_t)ci * HW];
        if (v >= 0.f) b |= 1ull << ci;
    }
    xp[(size_t)s * 4 + word] = b;
}

// ---- XNOR conv: 64 live accumulators, one tap in flight, bias LUT ----------
__global__ __launch_bounds__(256, 4) void conv_kernel(const u64* __restrict__ xp,
                                                      const u64* __restrict__ wp,
                                                      const unsigned short* __restrict__ pw,
                                                      short* __restrict__ y) {
    __shared__ __align__(16) u64 wlds[64 * 36];        // 18 KB: this block's 64 co
    __shared__ unsigned short blds[9 * 64];            // bias LUT per (border-class, co)
    int co0 = blockIdx.y * 64;
    for (int i = threadIdx.x; i < 64 * 36; i += 256)
        wlds[i] = wp[(size_t)co0 * 36 + i];
    for (int i = threadIdx.x; i < 9 * 64; i += 256) {
        int mi = i >> 6, c = i & 63;
        int rm = mi / 3, cm = mi % 3;
        int vr = rm == 0 ? 6 : (rm == 2 ? 3 : 7);      // valid-kh bitmask
        int vc = cm == 0 ? 6 : (cm == 2 ? 3 : 7);      // valid-kw bitmask
        int corr = 0;
        for (int kh = 0; kh < 3; ++kh)
            for (int kw = 0; kw < 3; ++kw)
                if (!(((vr >> kh) & 1) && ((vc >> kw) & 1)))
                    corr += pw[(co0 + c) * 9 + kh * 3 + kw];
        blds[i] = (unsigned short)(256 * __popc(vr) * __popc(vc) + 2 * corr);
    }
    __syncthreads();

    int s = blockIdx.x * 256 + threadIdx.x;   // pixel
    int n = s / HW, hw = s % HW;
    int h = hw / 56, w = hw % 56;
    int rm = (h < 2) ? 0 : (h > 53 ? 2 : 1);
    int cm = (w < 2) ? 0 : (w > 53 ? 2 : 1);
    int mi = rm * 3 + cm;
    const u64* xbase = xp + (size_t)(n * HW) * 4;

    int acc[64];
    #pragma unroll
    for (int c = 0; c < 64; ++c) acc[c] = 0;

    for (int kh = 0; kh < 3; ++kh) {                   // runtime tap loops
        int hh = h + 2 * kh - 2;
        int hc = hh < 0 ? 0 : (hh > 55 ? 55 : hh);
        for (int kw = 0; kw < 3; ++kw) {
            int ww = w + 2 * kw - 2;
            int wc = ww < 0 ? 0 : (ww > 55 ? 55 : ww);
            bool valid = (hh == hc) && (ww == wc);
            const u64* p = xbase + (hc * 56 + wc) * 4;
            u64 x0 = p[0], x1 = p[1], x2 = p[2], x3 = p[3];
            x0 = valid ? x0 : 0; x1 = valid ? x1 : 0;  // zeroed taps corrected by bias LUT
            x2 = valid ? x2 : 0; x3 = valid ? x3 : 0;
            int tb = (kh * 3 + kw) * 4;
            #pragma unroll
            for (int c = 0; c < 64; ++c) {             // 8 xor + 8 bcnt per channel
                const u64* wq = &wlds[c * 36 + tb];
                acc[c] = (int)__popcll(x0 ^ wq[0]) + acc[c];
                acc[c] = (int)__popcll(x1 ^ wq[1]) + acc[c];
                acc[c] = (int)__popcll(x2 ^ wq[2]) + acc[c];
                acc[c] = (int)__popcll(x3 ^ wq[3]) + acc[c];
            }
        }
    }

    short* yo = y + (size_t)(n * 256 + co0) * HW + hw;
    #pragma unroll
    for (int c = 0; c < 64; ++c) {
        int bias = blds[mi * 64 + c];
        yo[(size_t)c * HW] = (short)(bias - 2 * acc[c]);
    }
}

// ---- exact per-channel partial stats (2 batch-halves per channel) ----------
__global__ __launch_bounds__(256) void stats1_kernel(const short* __restrict__ y,
                                                     long long* __restrict__ part) {
    int c = blockIdx.x & 255, half = blockIdx.x >> 8;
    int tid = threadIdx.x;
    long long s1 = 0, s2 = 0;
    for (int n = half * 16; n < half * 16 + 16; ++n) {
        const short* p = y + (size_t)(n * 256 + c) * HW;
        for (int i = tid; i < 392; i += 256) {         // 392 short8 per plane
            int4 v = *(const int4*)(p + i * 8);
            int vs[4] = {v.x, v.y, v.z, v.w};
            int a = 0, q = 0;
            #pragma unroll
            for (int j = 0; j < 4; ++j) {
                int lo = (short)(vs[j] & 0xffff);
                int hi = (short)(vs[j] >> 16);
                a += lo + hi;
                q += lo * lo + hi * hi;
            }
            s1 += a; s2 += q;
        }
    }
    #pragma unroll
    for (int off = 32; off > 0; off >>= 1) {
        s1 += __shfl_down(s1, off);
        s2 += __shfl_down(s2, off);
    }
    __shared__ long long ls1[4], ls2[4];
    if ((tid & 63) == 0) { ls1[tid >> 6] = s1; ls2[tid >> 6] = s2; }
    __syncthreads();
    if (tid == 0) {
        part[blockIdx.x * 2]     = ls1[0] + ls1[1] + ls1[2] + ls1[3];
        part[blockIdx.x * 2 + 1] = ls2[0] + ls2[1] + ls2[2] + ls2[3];
    }
}

__global__ void stats2_kernel(const long long* __restrict__ part,
                              const float* __restrict__ gamma,
                              const float* __restrict__ beta,
                              float2* __restrict__ sc) {
    int c = threadIdx.x;
    double S1 = (double)(part[c * 2] + part[(256 + c) * 2]);
    double S2 = (double)(part[c * 2 + 1] + part[(256 + c) * 2 + 1]);
    double cnt = 100352.0;
    double mean = S1 / cnt;
    double var = S2 / cnt - mean * mean;
    float a = gamma[c] * rsqrtf((float)var + 1e-5f);
    float b = beta[c] - (float)mean * a;
    sc[c] = make_float2(a, b);
}

// ---- normalize + tanh, vectorized ------------------------------------------
__global__ __launch_bounds__(256) void norm_kernel(const short* __restrict__ y,
                                                   const float2* __restrict__ sc,
                                                   float* __restrict__ out) {
    size_t i = ((size_t)blockIdx.x * 256 + threadIdx.x) * 8;   // 8-groups never cross a plane
    int c = (int)((i / HW) & 255);
    float2 s = sc[c];
    int4 v = *(const int4*)(y + i);
    int vs[4] = {v.x, v.y, v.z, v.w};
    float r[8];
    #pragma unroll
    for (int j = 0; j < 4; ++j) {
        short lo = (short)(vs[j] & 0xffff);
        short hi = (short)(vs[j] >> 16);
        r[2 * j]     = tanhf(s.x * (float)lo + s.y);
        r[2 * j + 1] = tanhf(s.x * (float)hi + s.y);
    }
    *(float4*)(out + i)     = make_float4(r[0], r[1], r[2], r[3]);
    *(float4*)(out + i + 4) = make_float4(r[4], r[5], r[6], r[7]);
}

extern "C" void kernel_launch(void* const* d_in, const int* in_sizes, int n_in,
                              void* d_out, int out_size, void* d_ws, size_t ws_size,
                              hipStream_t stream) {
    const float* x     = (const float*)d_in[0];
    const float* W     = (const float*)d_in[1];
    const float* gamma = (const float*)d_in[2];
    const float* beta  = (const float*)d_in[3];
    float* out = (float*)d_out;

    char* ws = (char*)d_ws;
    short* y           = (short*)ws;                   // 51,380,224 B
    u64*  xp           = (u64*)(ws + 51380224);        //  3,211,264 B
    u64*  wp           = (u64*)(ws + 54591488);        //     73,728 B
    unsigned short* pw = (unsigned short*)(ws + 54665216); //  4,608 B
    float2* sc         = (float2*)(ws + 54669824);     //      2,048 B
    long long* part    = (long long*)(ws + 54671872);  //      8,192 B

    pack_w_kernel<<<9, 256, 0, stream>>>(W, wp, pw);
    pack_x_kernel<<<dim3(392, 4), 256, 0, stream>>>(x, xp);
    conv_kernel<<<dim3(392, 4), 256, 0, stream>>>(xp, wp, pw, y);
    stats1_kernel<<<512, 256, 0, stream>>>(y, part);
    stats2_kernel<<<1, 256, 0, stream>>>(part, gamma, beta, sc);
    norm_kernel<<<12544, 256, 0, stream>>>(y, sc, out);
}

// Round 4
// 255.581 us; speedup vs baseline: 1.2174x; 1.2174x over previous
//
#include <hip/hip_runtime.h>

typedef unsigned long long u64;

#define HW 3136      // 56*56
#define NPIX 100352  // 32*3136

// ---- pack weights: [co][tap] -> 4 x u64 (256 ci bits) + per-tap popcount ---
__global__ __launch_bounds__(256) void pack_w_kernel(const float* __restrict__ W,
                                                     u64* __restrict__ wp,
                                                     unsigned short* __restrict__ pw) {
    int t = blockIdx.x * 256 + threadIdx.x;   // co*9 + tap, 2304 total (9 blocks)
    int co = t / 9, tap = t % 9;
    u64 b[4] = {0, 0, 0, 0};
    for (int ci = 0; ci < 256; ++ci) {
        float v = W[(size_t)(co * 256 + ci) * 9 + tap];
        if (v >= 0.f) b[ci >> 6] |= 1ull << (ci & 63);
    }
    u64* dst = wp + (size_t)t * 4;
    dst[0] = b[0]; dst[1] = b[1]; dst[2] = b[2]; dst[3] = b[3];
    pw[t] = (unsigned short)(__popcll(b[0]) + __popcll(b[1]) + __popcll(b[2]) + __popcll(b[3]));
}

// ---- pack activations: [n][h][w] -> 4 x u64 --------------------------------
__global__ __launch_bounds__(256) void pack_x_kernel(const float* __restrict__ x,
                                                     u64* __restrict__ xp) {
    int s = blockIdx.x * 256 + threadIdx.x;   // pixel in [0, 100352)
    int word = blockIdx.y;                    // 0..3 (64 channels each)
    int n = s / HW, hw = s % HW;
    const float* px = x + (size_t)(n * 256 + word * 64) * HW + hw;
    u64 b = 0;
    #pragma unroll 8
    for (int ci = 0; ci < 64; ++ci) {
        float v = px[(size_t)ci * HW];
        if (v >= 0.f) b |= 1ull << ci;
    }
    xp[(size_t)s * 4 + word] = b;
}

// ---- XNOR conv: 16 channels/thread (acc provably in VGPRs), bias LUT -------
#define CPT 16   // channels per thread
__global__ __launch_bounds__(256) void conv_kernel(const u64* __restrict__ xp,
                                                   const u64* __restrict__ wp,
                                                   const unsigned short* __restrict__ pw,
                                                   short* __restrict__ y) {
    __shared__ __align__(16) u64 wlds[CPT * 36];       // this block's CPT co, 4.6 KB
    __shared__ unsigned short blds[9 * CPT];           // bias LUT per (border-class, co)
    int co0 = blockIdx.y * CPT;
    for (int i = threadIdx.x; i < CPT * 36; i += 256)
        wlds[i] = wp[(size_t)co0 * 36 + i];
    for (int i = threadIdx.x; i < 9 * CPT; i += 256) {
        int mi = i / CPT, c = i % CPT;
        int rm = mi / 3, cm = mi % 3;
        int vr = rm == 0 ? 6 : (rm == 2 ? 3 : 7);      // valid-kh bitmask
        int vc = cm == 0 ? 6 : (cm == 2 ? 3 : 7);      // valid-kw bitmask
        int corr = 0;
        for (int kh = 0; kh < 3; ++kh)
            for (int kw = 0; kw < 3; ++kw)
                if (!(((vr >> kh) & 1) && ((vc >> kw) & 1)))
                    corr += pw[(co0 + c) * 9 + kh * 3 + kw];
        blds[i] = (unsigned short)(256 * __popc(vr) * __popc(vc) + 2 * corr);
    }
    __syncthreads();

    int s = blockIdx.x * 256 + threadIdx.x;   // pixel
    int n = s / HW, hw = s % HW;
    int h = hw / 56, w = hw % 56;
    int rm = (h < 2) ? 0 : (h > 53 ? 2 : 1);
    int cm = (w < 2) ? 0 : (w > 53 ? 2 : 1);
    int mi = rm * 3 + cm;
    const u64* xbase = xp + (size_t)(n * HW) * 4;

    int acc[CPT];
    #pragma unroll
    for (int c = 0; c < CPT; ++c) acc[c] = 0;

    for (int kh = 0; kh < 3; ++kh) {                   // runtime tap loops
        int hh = h + 2 * kh - 2;
        int hc = hh < 0 ? 0 : (hh > 55 ? 55 : hh);
        for (int kw = 0; kw < 3; ++kw) {
            int ww = w + 2 * kw - 2;
            int wc = ww < 0 ? 0 : (ww > 55 ? 55 : ww);
            bool valid = (hh == hc) && (ww == wc);
            const u64* p = xbase + (hc * 56 + wc) * 4;
            u64 x0 = p[0], x1 = p[1], x2 = p[2], x3 = p[3];
            x0 = valid ? x0 : 0; x1 = valid ? x1 : 0;  // zeroed taps corrected by bias LUT
            x2 = valid ? x2 : 0; x3 = valid ? x3 : 0;
            int tb = (kh * 3 + kw) * 4;
            #pragma unroll
            for (int c = 0; c < CPT; ++c) {            // 8 xor + 8 bcnt per channel
                const u64* wq = &wlds[c * 36 + tb];
                acc[c] = (int)__popcll(x0 ^ wq[0]) + acc[c];
                acc[c] = (int)__popcll(x1 ^ wq[1]) + acc[c];
                acc[c] = (int)__popcll(x2 ^ wq[2]) + acc[c];
                acc[c] = (int)__popcll(x3 ^ wq[3]) + acc[c];
            }
        }
    }

    short* yo = y + (size_t)(n * 256 + co0) * HW + hw;
    #pragma unroll
    for (int c = 0; c < CPT; ++c) {
        int bias = blds[mi * CPT + c];
        yo[(size_t)c * HW] = (short)(bias - 2 * acc[c]);
    }
}

// ---- exact per-channel partial stats (2 batch-halves per channel) ----------
__global__ __launch_bounds__(256) void stats1_kernel(const short* __restrict__ y,
                                                     long long* __restrict__ part) {
    int c = blockIdx.x & 255, half = blockIdx.x >> 8;
    int tid = threadIdx.x;
    long long s1 = 0, s2 = 0;
    for (int n = half * 16; n < half * 16 + 16; ++n) {
        const short* p = y + (size_t)(n * 256 + c) * HW;
        for (int i = tid; i < 392; i += 256) {         // 392 short8 per plane
            int4 v = *(const int4*)(p + i * 8);
            int vs[4] = {v.x, v.y, v.z, v.w};
            int a = 0, q = 0;
            #pragma unroll
            for (int j = 0; j < 4; ++j) {
                int lo = (short)(vs[j] & 0xffff);
                int hi = (short)(vs[j] >> 16);
                a += lo + hi;
                q += lo * lo + hi * hi;
            }
            s1 += a; s2 += q;
        }
    }
    #pragma unroll
    for (int off = 32; off > 0; off >>= 1) {
        s1 += __shfl_down(s1, off);
        s2 += __shfl_down(s2, off);
    }
    __shared__ long long ls1[4], ls2[4];
    if ((tid & 63) == 0) { ls1[tid >> 6] = s1; ls2[tid >> 6] = s2; }
    __syncthreads();
    if (tid == 0) {
        part[blockIdx.x * 2]     = ls1[0] + ls1[1] + ls1[2] + ls1[3];
        part[blockIdx.x * 2 + 1] = ls2[0] + ls2[1] + ls2[2] + ls2[3];
    }
}

__global__ void stats2_kernel(const long long* __restrict__ part,
                              const float* __restrict__ gamma,
                              const float* __restrict__ beta,
                              float2* __restrict__ sc) {
    int c = threadIdx.x;
    double S1 = (double)(part[c * 2] + part[(256 + c) * 2]);
    double S2 = (double)(part[c * 2 + 1] + part[(256 + c) * 2 + 1]);
    double cnt = 100352.0;
    double mean = S1 / cnt;
    double var = S2 / cnt - mean * mean;
    float a = gamma[c] * rsqrtf((float)var + 1e-5f);
    float b = beta[c] - (float)mean * a;
    sc[c] = make_float2(a, b);
}

// ---- normalize + tanh, vectorized ------------------------------------------
__global__ __launch_bounds__(256) void norm_kernel(const short* __restrict__ y,
                                                   const float2* __restrict__ sc,
                                                   float* __restrict__ out) {
    size_t i = ((size_t)blockIdx.x * 256 + threadIdx.x) * 8;   // 8-groups never cross a plane
    int c = (int)((i / HW) & 255);
    float2 s = sc[c];
    int4 v = *(const int4*)(y + i);
    int vs[4] = {v.x, v.y, v.z, v.w};
    float r[8];
    #pragma unroll
    for (int j = 0; j < 4; ++j) {
        short lo = (short)(vs[j] & 0xffff);
        short hi = (short)(vs[j] >> 16);
        r[2 * j]     = tanhf(s.x * (float)lo + s.y);
        r[2 * j + 1] = tanhf(s.x * (float)hi + s.y);
    }
    *(float4*)(out + i)     = make_float4(r[0], r[1], r[2], r[3]);
    *(float4*)(out + i + 4) = make_float4(r[4], r[5], r[6], r[7]);
}

extern "C" void kernel_launch(void* const* d_in, const int* in_sizes, int n_in,
                              void* d_out, int out_size, void* d_ws, size_t ws_size,
                              hipStream_t stream) {
    const float* x     = (const float*)d_in[0];
    const float* W     = (const float*)d_in[1];
    const float* gamma = (const float*)d_in[2];
    const float* beta  = (const float*)d_in[3];
    float* out = (float*)d_out;

    char* ws = (char*)d_ws;
    short* y           = (short*)ws;                   // 51,380,224 B
    u64*  xp           = (u64*)(ws + 51380224);        //  3,211,264 B
    u64*  wp           = (u64*)(ws + 54591488);        //     73,728 B
    unsigned short* pw = (unsigned short*)(ws + 54665216); //  4,608 B
    float2* sc         = (float2*)(ws + 54669824);     //      2,048 B
    long long* part    = (long long*)(ws + 54671872);  //      8,192 B

    pack_w_kernel<<<9, 256, 0, stream>>>(W, wp, pw);
    pack_x_kernel<<<dim3(392, 4), 256, 0, stream>>>(x, xp);
    conv_kernel<<<dim3(392, 16), 256, 0, stream>>>(xp, wp, pw, y);
    stats1_kernel<<<512, 256, 0, stream>>>(y, part);
    stats2_kernel<<<1, 256, 0, stream>>>(part, gamma, beta, sc);
    norm_kernel<<<12544, 256, 0, stream>>>(y, sc, out);
}